// Round 4
// baseline (221.706 us; speedup 1.0000x reference)
//
#include <hip/hip_runtime.h>

// Problem: B=64, K=17, H=128, W=128, RATIO=0.25, SIGMA=2.0
constexpr int   HW     = 16384;
constexpr int   NT1    = 256;            // threads/block, select kernel
constexpr int   V4     = 16;             // float4 per thread (select pass 1)
constexpr int   GTMAX  = 4096;           // #(v > thresh) for kthvalue(12288)
constexpr int   NSLICE = 1088;           // 64*17
constexpr int   SLOTS  = 16;             // per-thread stash capacity (P(overflow) ~ 1e-11)
constexpr int   SSTR   = 17;             // stash stride (bank-conflict pad)
constexpr int   BINS   = 2048;           // counting-refine buckets over the bracket
constexpr float LO0    = 0.735f;         // static bracket around the 0.75-quantile
constexpr float HI0    = 0.770f;         // (runtime-validated; exact fallback otherwise)
constexpr float BSCALE = (float)BINS / (HI0 - LO0);
constexpr int   NG4    = NSLICE * (HW / 4);   // 4,456,448 float4 groups
constexpr int   SGRID  = 4352;           // stream kernel grid: exactly 4 iters/thread

__device__ __forceinline__ int bucket_of(float x) {
    int b = (int)((x - LO0) * BSCALE);   // monotone in x
    return b < 0 ? 0 : (b > BINS - 1 ? BINS - 1 : b);
}

// Kernel 1: per-slice argmax + exact kthvalue threshold + Gaussian-box correction.
__global__ __launch_bounds__(NT1) void wreg_select(
    const float* __restrict__ pred,
    const float* __restrict__ tgt,
    float* __restrict__ partial,
    float* __restrict__ thtab)
{
    __shared__ int   hist[BINS];           // 8 KB
    __shared__ float stash[NT1 * SSTR];    // 17 KB
    __shared__ float redf[4];
    __shared__ int   redi[4];
    __shared__ int   whi[4], wwin[4], wovf[4], wcnt[4], wtot[4];
    __shared__ float cands[64];
    __shared__ int   s_nc;
    __shared__ int   s_bstar, s_above;
    __shared__ float s_th;

    const int t = threadIdx.x, lane = t & 63, wid = t >> 6;
    const int bid = blockIdx.x;
    const float4* t4 = reinterpret_cast<const float4*>(tgt) + (size_t)bid * (HW / 4);

    #pragma unroll
    for (int i = t; i < BINS; i += NT1) hist[i] = 0;
    if (t == 0) s_nc = 0;

    // ---- Pass 1 (the only full read of tgt): argmax + bracket counts + stash ----
    float bmax = -1.f; int bmi = 0;
    int cnt_hi = 0, myn = 0, ovf = 0;
    const int sbase = t * SSTR;
    #pragma unroll
    for (int j = 0; j < V4; ++j) {
        const int vi = j * NT1 + t;
        float4 v = t4[vi];
        const int base = vi * 4;
        float a[4] = {v.x, v.y, v.z, v.w};
        #pragma unroll
        for (int c = 0; c < 4; ++c) {
            float x = a[c];
            if (x > bmax) { bmax = x; bmi = base + c; }  // per-thread idx increasing
            cnt_hi += (x > HI0) ? 1 : 0;
            if (x > LO0 && x <= HI0) {
                if (myn < SLOTS) stash[sbase + myn] = x; else ovf = 1;
                ++myn;
            }
        }
    }
    const int mynv = myn > SLOTS ? SLOTS : myn;

    // ---- One combined block reduce: argmax pair + three sums ----
    float am = bmax; int ai = bmi;
    int rh = cnt_hi, rw = myn, ro = ovf;
    #pragma unroll
    for (int off = 32; off > 0; off >>= 1) {
        float ov = __shfl_down(am, off); int oi = __shfl_down(ai, off);
        int o1 = __shfl_down(rh, off), o2 = __shfl_down(rw, off), o3 = __shfl_down(ro, off);
        if (ov > am || (ov == am && oi < ai)) { am = ov; ai = oi; }
        rh += o1; rw += o2; ro |= o3;
    }
    if (lane == 0) { redf[wid] = am; redi[wid] = ai; whi[wid] = rh; wwin[wid] = rw; wovf[wid] = ro; }
    __syncthreads();   // also orders hist zeroing before atomics below
    float mv = redf[0]; int mi = redi[0];
    int g_hi0 = 0, win = 0, anyovf = 0;
    #pragma unroll
    for (int w = 0; w < 4; ++w) {
        if (redf[w] > mv || (redf[w] == mv && redi[w] < mi)) { mv = redf[w]; mi = redi[w]; }
        g_hi0 += whi[w]; win += wwin[w]; anyovf |= wovf[w];
    }
    const int need = (GTMAX + 1) - g_hi0;       // rank-from-top inside the window
    const bool valid = (!anyovf) && (g_hi0 <= GTMAX) && (need <= win);

    float th = 0.f;
    bool done = false;   // block-uniform by construction

    if (valid) {
        // ---- Counting refinement: one histogram, one suffix scan, exact bucket ----
        for (int k = 0; k < mynv; ++k)
            atomicAdd(&hist[bucket_of(stash[sbase + k])], 1);
        __syncthreads();
        int h[8];
        #pragma unroll
        for (int q = 0; q < 8; ++q) h[q] = hist[t * 8 + q];
        int lsum = 0;
        #pragma unroll
        for (int q = 0; q < 8; ++q) lsum += h[q];
        int incl = lsum;                         // wave suffix-inclusive scan
        #pragma unroll
        for (int off = 1; off < 64; off <<= 1) {
            int v = __shfl_down(incl, off);
            incl += (lane + off < 64) ? v : 0;
        }
        if (lane == 0) wtot[wid] = incl;
        __syncthreads();
        int sufHigher = incl - lsum;
        #pragma unroll
        for (int w = 0; w < 4; ++w) sufHigher += (w > wid) ? wtot[w] : 0;
        int running = sufHigher;                 // cumTop above each of my buckets
        #pragma unroll
        for (int q = 7; q >= 0; --q) {
            int cum = running + h[q];
            if (running < need && need <= cum) { s_bstar = t * 8 + q; s_above = running; }
            running = cum;
        }
        __syncthreads();
        const int bstar = s_bstar, above = s_above;
        const int c = hist[bstar];               // block-uniform
        if (c <= 64) {
            for (int k = 0; k < mynv; ++k) {
                float x = stash[sbase + k];
                if (bucket_of(x) == bstar) { int pos = atomicAdd(&s_nc, 1); cands[pos] = x; }
            }
            __syncthreads();
            const int m = s_nc;                  // == c, tiny (usually 1-3)
            for (int i = t; i < m; i += NT1) {
                float ci = cands[i];
                int gt = 0, eq = 0;
                for (int j2 = 0; j2 < m; ++j2) {
                    float cj = cands[j2];
                    gt += (cj > ci) ? 1 : 0; eq += (cj == ci) ? 1 : 0;
                }
                int gg = g_hi0 + above + gt;
                if (gg <= GTMAX && gg + eq >= GTMAX + 1) s_th = ci;
            }
            __syncthreads();
            th = s_th;
            done = true;
        }
    }
    if (!done) {
        // ---- Exact fallback (rare): value bisection re-reading tgt (L2-hot) ----
        float lo = -1.0f, hi = mv;
        int g_lo = HW, g_hi = 0;
        bool degen = false;
        while (g_lo - g_hi > 48) {
            float mid = 0.5f * (lo + hi);
            if (!(mid > lo && mid < hi)) { degen = true; break; }
            int cnt = 0;
            for (int j = 0; j < V4; ++j) {
                float4 v = t4[j * NT1 + t];
                cnt += (v.x > mid) + (v.y > mid) + (v.z > mid) + (v.w > mid);
            }
            #pragma unroll
            for (int off = 32; off > 0; off >>= 1) cnt += __shfl_down(cnt, off);
            if (lane == 0) wcnt[wid] = cnt;
            __syncthreads();
            int g = wcnt[0] + wcnt[1] + wcnt[2] + wcnt[3];
            __syncthreads();
            if (g >= GTMAX + 1) { lo = mid; g_lo = g; }
            else                { hi = mid; g_hi = g; }
        }
        if (degen) th = hi;   // all window values identical to hi
        else {
            if (t == 0) s_nc = 0;
            __syncthreads();
            for (int j = 0; j < V4; ++j) {
                float4 v = t4[j * NT1 + t];
                float a[4] = {v.x, v.y, v.z, v.w};
                for (int c2 = 0; c2 < 4; ++c2) {
                    float x = a[c2];
                    if (x > lo && x <= hi) { int pos = atomicAdd(&s_nc, 1); if (pos < 64) cands[pos] = x; }
                }
            }
            __syncthreads();
            int m = s_nc; m = m > 64 ? 64 : m;
            for (int i = t; i < m; i += NT1) {
                float ci = cands[i];
                int gt = 0, eq = 0;
                for (int j2 = 0; j2 < m; ++j2) {
                    float cj = cands[j2];
                    gt += (cj > ci) ? 1 : 0; eq += (cj == ci) ? 1 : 0;
                }
                int gg = g_hi + gt;
                if (gg <= GTMAX && gg + eq >= GTMAX + 1) s_th = ci;
            }
            __syncthreads();
            th = s_th;
        }
    }

    // ---- Gaussian-box correction: sum mask*(g^2 - 2*p*g) over 31x31 around argmax.
    // Outside the box g <= e^-32 ~ 1.3e-14 -> neglected (error ~1e-11 << 2e-2 tol).
    const int cyi = mi >> 7, cxi = mi & 127;
    const float* tbase = tgt  + (size_t)bid * HW;
    const float* pbase = pred + (size_t)bid * HW;
    float corr = 0.f;
    for (int i = t; i < 961; i += NT1) {
        int dy = i / 31 - 15;
        int dx = i - (i / 31) * 31 - 15;
        int y = cyi + dy, x = cxi + dx;
        if ((unsigned)y < 128u && (unsigned)x < 128u) {
            int o = (y << 7) + x;
            float tv = tbase[o];
            float pv = pbase[o];
            if (tv > th) {
                float d2 = (float)(dy * dy + dx * dx);
                float g = __expf(d2 * -0.125f);          // exp(-d2/(2*sigma^2))
                corr += g * (g - 2.0f * pv);             // (p-g)^2 - p^2
            }
        }
    }
    #pragma unroll
    for (int off = 32; off > 0; off >>= 1) corr += __shfl_down(corr, off);
    __syncthreads();
    if (lane == 0) redf[wid] = corr;
    __syncthreads();
    if (t == 0) {
        partial[bid] = redf[0] + redf[1] + redf[2] + redf[3];   // init + correction
        thtab[bid]   = th;
    }
}

// Kernel 2: barrier-free streaming sum of mask * pred^2 (runs at memory speed).
__global__ __launch_bounds__(256) void wreg_stream(
    const float* __restrict__ pred,
    const float* __restrict__ tgt,
    const float* __restrict__ thtab,
    float* __restrict__ partial)
{
    const int lane = threadIdx.x & 63;
    const float4* t4 = reinterpret_cast<const float4*>(tgt);
    const float4* p4 = reinterpret_cast<const float4*>(pred);
    for (int i = blockIdx.x * 256 + threadIdx.x; i < NG4; i += SGRID * 256) {
        const int slice = i >> 12;            // 4096 groups/slice; wave-uniform
        const float th = thtab[slice];
        float4 tv = t4[i];
        float4 pv = p4[i];
        float s = 0.f;
        s += (tv.x > th) ? pv.x * pv.x : 0.f;
        s += (tv.y > th) ? pv.y * pv.y : 0.f;
        s += (tv.z > th) ? pv.z * pv.z : 0.f;
        s += (tv.w > th) ? pv.w * pv.w : 0.f;
        #pragma unroll
        for (int off = 32; off > 0; off >>= 1) s += __shfl_down(s, off);
        if (lane == 0) atomicAdd(&partial[slice], s);
    }
}

__global__ __launch_bounds__(256) void wreg_final(
    const float* __restrict__ partial, float* __restrict__ out)
{
    __shared__ float red[4];
    const int t = threadIdx.x;
    float s = 0.f;
    for (int i = t; i < NSLICE; i += 256) s += partial[i];
    #pragma unroll
    for (int off = 32; off > 0; off >>= 1) s += __shfl_down(s, off);
    if ((t & 63) == 0) red[t >> 6] = s;
    __syncthreads();
    if (t == 0)
        out[0] = ((red[0] + red[1]) + (red[2] + red[3]))
                 * (1.0f / ((float)(HW / 4) * (float)NSLICE));  // / pxl_num / (B*K)
}

extern "C" void kernel_launch(void* const* d_in, const int* in_sizes, int n_in,
                              void* d_out, int out_size, void* d_ws, size_t ws_size,
                              hipStream_t stream)
{
    const float* pred = (const float*)d_in[0];   // "output" in reference
    const float* tgt  = (const float*)d_in[1];   // "target"
    float* partial = (float*)d_ws;               // [0, 1088): per-slice sums
    float* thtab   = (float*)d_ws + NSLICE;      // [1088, 2176): thresholds
    float* out     = (float*)d_out;

    wreg_select<<<NSLICE, NT1, 0, stream>>>(pred, tgt, partial, thtab);
    wreg_stream<<<SGRID, 256, 0, stream>>>(pred, tgt, thtab, partial);
    wreg_final <<<1, 256, 0, stream>>>(partial, out);
}

// Round 5
// 185.936 us; speedup vs baseline: 1.1924x; 1.1924x over previous
//
#include <hip/hip_runtime.h>

// Problem: B=64, K=17, H=128, W=128, RATIO=0.25, SIGMA=2.0
constexpr int   HW     = 16384;
constexpr int   NT     = 256;            // threads per block; 1 block per slice
constexpr int   V4     = 16;             // float4 groups per thread (64 elems/thread)
constexpr int   GTMAX  = 4096;           // #(v > thresh) for kthvalue rank 12288
constexpr int   NSLICE = 1088;           // 64*17
constexpr int   SLOTS  = 12;             // per-thread stash (window mean 2.24, P(ovf block)~3e-5)
constexpr int   SSTR   = 13;             // stash stride pad
constexpr int   BINS   = 2048;           // counting-refinement buckets
constexpr float LO0    = 0.735f;         // static bracket around 0.75-quantile of U(0,1)
constexpr float HI0    = 0.770f;         // runtime-validated; exact fallback otherwise
constexpr float BSCALE = (float)BINS / (HI0 - LO0);

__device__ __forceinline__ int bucket_of(float x) {
    int b = (int)((x - LO0) * BSCALE);   // monotone in x on (LO0, HI0]
    return b < 0 ? 0 : (b > BINS - 1 ? BINS - 1 : b);
}

__global__ __launch_bounds__(NT) void wreg_fused(
    const float* __restrict__ pred,
    const float* __restrict__ tgt,
    float* __restrict__ partial)
{
    __shared__ int   hist[BINS];          // 8 KB
    __shared__ float sval[NT * SSTR];     // 13.3 KB
    __shared__ float redf[4];
    __shared__ int   redi[4];
    __shared__ int   whi[4], wwin[4], wovf[4], wcnt[4], wtot[4];
    __shared__ float cands[64];
    __shared__ int   s_nc, s_bstar, s_above;
    __shared__ float s_th;

    const int t = threadIdx.x, lane = t & 63, wid = t >> 6;
    const int bid = blockIdx.x;
    const float4* t4 = reinterpret_cast<const float4*>(tgt)  + (size_t)bid * (HW / 4);
    const float4* p4 = reinterpret_cast<const float4*>(pred) + (size_t)bid * (HW / 4);
    const int sbase = t * SSTR;

    #pragma unroll
    for (int i = t; i < BINS; i += NT) hist[i] = 0;
    if (t == 0) s_nc = 0;

    // ---- Pass 1: stream tgt once. Argmax + 64-bit hi/win masks + window stash ----
    float bmax = -1.f; int bmi = 0;
    int myn = 0;
    unsigned long long hib = 0ull, wib = 0ull;
    #pragma unroll
    for (int j = 0; j < V4; ++j) {
        const int vi = j * NT + t;
        float4 v = t4[vi];
        const int base = vi * 4;
        float a[4] = {v.x, v.y, v.z, v.w};
        #pragma unroll
        for (int c = 0; c < 4; ++c) {
            float x = a[c];
            if (x > bmax) { bmax = x; bmi = base + c; }        // per-thread idx increasing
            hib |= (unsigned long long)(x > HI0) << (j * 4 + c);
            if (x > LO0 && x <= HI0) {
                wib |= 1ull << (j * 4 + c);
                if (myn < SLOTS) sval[sbase + myn] = x;
                ++myn;
            }
        }
    }
    const int mynv = myn > SLOTS ? SLOTS : myn;

    // ---- One combined block reduce: argmax + #(>HI0) + window count + overflow ----
    {
        float am = bmax; int ai = bmi;
        int rh = __popcll(hib), rw = myn, ro = (myn > SLOTS) ? 1 : 0;
        #pragma unroll
        for (int off = 32; off > 0; off >>= 1) {
            float ov = __shfl_down(am, off); int oi = __shfl_down(ai, off);
            int o1 = __shfl_down(rh, off), o2 = __shfl_down(rw, off), o3 = __shfl_down(ro, off);
            if (ov > am || (ov == am && oi < ai)) { am = ov; ai = oi; }
            rh += o1; rw += o2; ro |= o3;
        }
        if (lane == 0) { redf[wid] = am; redi[wid] = ai; whi[wid] = rh; wwin[wid] = rw; wovf[wid] = ro; }
    }
    __syncthreads();   // also orders hist zeroing before histogram atomics
    float mv = redf[0]; int mi = redi[0];
    int g_hi0 = 0, win = 0, anyovf = 0;
    #pragma unroll
    for (int w = 0; w < 4; ++w) {
        if (redf[w] > mv || (redf[w] == mv && redi[w] < mi)) { mv = redf[w]; mi = redi[w]; }
        g_hi0 += whi[w]; win += wwin[w]; anyovf |= wovf[w];
    }
    const int need = (GTMAX + 1) - g_hi0;   // rank-from-top within the window
    const bool valid = (!anyovf) && (g_hi0 <= GTMAX) && (need <= win);

    float th = 0.f;
    bool done = false;   // block-uniform throughout

    if (valid) {
        // ---- Counting refinement: histogram stash, suffix-scan, exact tiny rank ----
        for (int k = 0; k < mynv; ++k)
            atomicAdd(&hist[bucket_of(sval[sbase + k])], 1);
        __syncthreads();
        int h[8];
        #pragma unroll
        for (int q = 0; q < 8; ++q) h[q] = hist[t * 8 + q];
        int lsum = 0;
        #pragma unroll
        for (int q = 0; q < 8; ++q) lsum += h[q];
        int incl = lsum;                        // wave suffix-inclusive scan
        #pragma unroll
        for (int off = 1; off < 64; off <<= 1) {
            int v = __shfl_down(incl, off);
            incl += (lane + off < 64) ? v : 0;
        }
        if (lane == 0) wtot[wid] = incl;
        __syncthreads();
        int suf = incl - lsum;
        #pragma unroll
        for (int w = 0; w < 4; ++w) suf += (w > wid) ? wtot[w] : 0;
        int running = suf;
        #pragma unroll
        for (int q = 7; q >= 0; --q) {
            int cum = running + h[q];
            if (running < need && need <= cum) { s_bstar = t * 8 + q; s_above = running; }
            running = cum;
        }
        __syncthreads();
        const int bstar = s_bstar, above = s_above;
        const int cnum = hist[bstar];           // block-uniform
        if (cnum <= 64) {
            for (int k = 0; k < mynv; ++k) {
                float x = sval[sbase + k];
                if (bucket_of(x) == bstar) { int pos = atomicAdd(&s_nc, 1); cands[pos] = x; }
            }
            __syncthreads();
            const int m = s_nc;                 // == cnum, usually 1-3
            for (int i = t; i < m; i += NT) {
                float ci = cands[i];
                int gt = 0, eq = 0;
                for (int j2 = 0; j2 < m; ++j2) {
                    float cj = cands[j2];
                    gt += (cj > ci) ? 1 : 0; eq += (cj == ci) ? 1 : 0;
                }
                int gg = g_hi0 + above + gt;
                if (gg <= GTMAX && gg + eq >= GTMAX + 1) s_th = ci;
            }
            __syncthreads();
            th = s_th;
            done = true;
        }
    }
    const bool fb = !done;
    if (fb) {
        // ---- Exact fallback (rare): value bisection re-reading tgt (L2/L3-hot) ----
        float lo = -1.0f, hi = mv;
        int g_lo = HW, g_hi = 0;
        bool degen = false;
        while (g_lo - g_hi > 48) {
            float mid = 0.5f * (lo + hi);
            if (!(mid > lo && mid < hi)) { degen = true; break; }
            int cnt = 0;
            for (int j = 0; j < V4; ++j) {
                float4 v = t4[j * NT + t];
                cnt += (v.x > mid) + (v.y > mid) + (v.z > mid) + (v.w > mid);
            }
            #pragma unroll
            for (int off = 32; off > 0; off >>= 1) cnt += __shfl_down(cnt, off);
            if (lane == 0) wcnt[wid] = cnt;
            __syncthreads();
            int g = wcnt[0] + wcnt[1] + wcnt[2] + wcnt[3];
            __syncthreads();
            if (g >= GTMAX + 1) { lo = mid; g_lo = g; }
            else                { hi = mid; g_hi = g; }
        }
        if (degen) th = hi;
        else {
            if (t == 0) s_nc = 0;
            __syncthreads();
            for (int j = 0; j < V4; ++j) {
                float4 v = t4[j * NT + t];
                float a[4] = {v.x, v.y, v.z, v.w};
                for (int c2 = 0; c2 < 4; ++c2) {
                    float x = a[c2];
                    if (x > lo && x <= hi) { int pos = atomicAdd(&s_nc, 1); if (pos < 64) cands[pos] = x; }
                }
            }
            __syncthreads();
            int m = s_nc; m = m > 64 ? 64 : m;
            for (int i = t; i < m; i += NT) {
                float ci = cands[i];
                int gt = 0, eq = 0;
                for (int j2 = 0; j2 < m; ++j2) {
                    float cj = cands[j2];
                    gt += (cj > ci) ? 1 : 0; eq += (cj == ci) ? 1 : 0;
                }
                int gg = g_hi + gt;
                if (gg <= GTMAX && gg + eq >= GTMAX + 1) s_th = ci;
            }
            __syncthreads();
            th = s_th;
        }
    }

    // ---- Pass 2: stream pred once; mask from hi-bits + stash pops (no tgt re-read) ----
    float sum = 0.f;
    if (!fb) {
        int k = 0;
        #pragma unroll
        for (int j = 0; j < V4; ++j) {
            const int vi = j * NT + t;
            float4 p = p4[vi];
            unsigned hbn = (unsigned)(hib >> (j * 4)) & 0xFu;
            unsigned wbn = (unsigned)(wib >> (j * 4)) & 0xFu;
            if (wbn == 0u) {   // common case: mask fully decided by hi-bits
                if (hbn & 1u) sum += p.x * p.x;
                if (hbn & 2u) sum += p.y * p.y;
                if (hbn & 4u) sum += p.z * p.z;
                if (hbn & 8u) sum += p.w * p.w;
            } else {
                float ap[4] = {p.x, p.y, p.z, p.w};
                #pragma unroll
                for (int c = 0; c < 4; ++c) {
                    bool m = (hbn >> c) & 1u;
                    if ((wbn >> c) & 1u) { float x = sval[sbase + k]; ++k; m = (x > th); }
                    if (m) sum += ap[c] * ap[c];
                }
            }
        }
    } else {
        for (int j = 0; j < V4; ++j) {
            const int vi = j * NT + t;
            float4 p = p4[vi];
            float4 tv = t4[vi];
            sum += (tv.x > th) ? p.x * p.x : 0.f;
            sum += (tv.y > th) ? p.y * p.y : 0.f;
            sum += (tv.z > th) ? p.z * p.z : 0.f;
            sum += (tv.w > th) ? p.w * p.w : 0.f;
        }
    }

    // ---- Gaussian box correction: mask*(g^2 - 2*p*g) over 31x31 around argmax.
    // Outside the box g <= e^-32 ~ 1.3e-14 -> error ~1e-11 << 2e-2 tol (verified R4).
    const int cyi = mi >> 7, cxi = mi & 127;
    const float* tbase = tgt  + (size_t)bid * HW;
    const float* pbase = pred + (size_t)bid * HW;
    for (int i = t; i < 961; i += NT) {
        int dy = i / 31 - 15;
        int dx = i - (i / 31) * 31 - 15;
        int y = cyi + dy, x = cxi + dx;
        if ((unsigned)y < 128u && (unsigned)x < 128u) {
            int o = (y << 7) + x;
            float tv = tbase[o];
            if (tv > th) {
                float pv = pbase[o];
                float d2 = (float)(dy * dy + dx * dx);
                float g = __expf(d2 * -0.125f);     // exp(-d2/(2*sigma^2))
                sum += g * (g - 2.0f * pv);         // (p-g)^2 - p^2
            }
        }
    }

    // ---- Block reduce, one plain store ----
    #pragma unroll
    for (int off = 32; off > 0; off >>= 1) sum += __shfl_down(sum, off);
    __syncthreads();                 // redf reuse guard
    if (lane == 0) redf[wid] = sum;
    __syncthreads();
    if (t == 0) partial[bid] = (redf[0] + redf[1]) + (redf[2] + redf[3]);
}

__global__ __launch_bounds__(256) void wreg_final(
    const float* __restrict__ partial, float* __restrict__ out)
{
    __shared__ float red[4];
    const int t = threadIdx.x;
    float s = 0.f;
    for (int i = t; i < NSLICE; i += 256) s += partial[i];
    #pragma unroll
    for (int off = 32; off > 0; off >>= 1) s += __shfl_down(s, off);
    if ((t & 63) == 0) red[t >> 6] = s;
    __syncthreads();
    if (t == 0)
        out[0] = ((red[0] + red[1]) + (red[2] + red[3]))
                 * (1.0f / ((float)(HW / 4) * (float)NSLICE));  // / pxl_num / (B*K)
}

extern "C" void kernel_launch(void* const* d_in, const int* in_sizes, int n_in,
                              void* d_out, int out_size, void* d_ws, size_t ws_size,
                              hipStream_t stream)
{
    const float* pred = (const float*)d_in[0];   // "output" in reference
    const float* tgt  = (const float*)d_in[1];   // "target"
    float* partial = (float*)d_ws;               // 1088 floats scratch
    float* out     = (float*)d_out;

    wreg_fused<<<NSLICE, NT, 0, stream>>>(pred, tgt, partial);
    wreg_final<<<1, 256, 0, stream>>>(partial, out);
}

// Round 6
// 168.749 us; speedup vs baseline: 1.3138x; 1.1018x over previous
//
#include <hip/hip_runtime.h>

// Problem: B=64, K=17, H=128, W=128, RATIO=0.25, SIGMA=2.0
constexpr int   HW     = 16384;
constexpr int   NT     = 512;            // threads per block; 1 block per slice
constexpr int   NWV    = 8;              // waves per block
constexpr int   V4     = 8;              // float4 groups per thread (32 elems/thread)
constexpr int   GTMAX  = 4096;           // #(v > thresh) for kthvalue rank 12288
constexpr int   NSLICE = 1088;           // 64*17
constexpr int   SLOTS  = 10;             // per-thread stash (mean 1.12, P(ovf/launch)~2e-2)
constexpr int   SSTR   = 11;             // stash stride pad
constexpr int   BINS   = 1024;           // counting-refinement buckets
constexpr float LO0    = 0.735f;         // static bracket around 0.75-quantile of U(0,1)
constexpr float HI0    = 0.770f;         // runtime-validated; exact fallback otherwise
constexpr float BSCALE = (float)BINS / (HI0 - LO0);

__device__ __forceinline__ int bucket_of(float x) {
    int b = (int)((x - LO0) * BSCALE);   // monotone in x on (LO0, HI0]
    return b < 0 ? 0 : (b > BINS - 1 ? BINS - 1 : b);
}

__global__ __launch_bounds__(NT, 6) void wreg_fused(
    const float* __restrict__ pred,
    const float* __restrict__ tgt,
    float* __restrict__ partial)
{
    __shared__ int   hist[BINS];          // 4 KB
    __shared__ float sval[NT * SSTR];     // 22.5 KB
    __shared__ float redf[NWV];
    __shared__ int   redi[NWV];
    __shared__ int   whi[NWV], wwin[NWV], wovf[NWV], wcnt[NWV], wtot[NWV];
    __shared__ float cands[64];
    __shared__ int   s_nc, s_bstar, s_above;
    __shared__ float s_th;

    const int t = threadIdx.x, lane = t & 63, wid = t >> 6;
    const int bid = blockIdx.x;
    const float4* t4 = reinterpret_cast<const float4*>(tgt)  + (size_t)bid * (HW / 4);
    const float4* p4 = reinterpret_cast<const float4*>(pred) + (size_t)bid * (HW / 4);
    const int sbase = t * SSTR;

    #pragma unroll
    for (int i = t; i < BINS; i += NT) hist[i] = 0;
    if (t == 0) s_nc = 0;

    // ---- Pass 1: stream tgt once. 8 loads issued up-front (MLP), then process ----
    float4 va[V4];
    #pragma unroll
    for (int j = 0; j < V4; ++j) va[j] = t4[j * NT + t];

    float bmax = -1.f; int bmi = 0;
    int myn = 0;
    unsigned hib = 0u, wib = 0u;          // 1 bit per element (32 elems/thread)
    #pragma unroll
    for (int j = 0; j < V4; ++j) {
        const int base = (j * NT + t) * 4;
        float a[4] = {va[j].x, va[j].y, va[j].z, va[j].w};
        #pragma unroll
        for (int c = 0; c < 4; ++c) {
            float x = a[c];
            if (x > bmax) { bmax = x; bmi = base + c; }   // per-thread idx increasing
            hib |= (unsigned)(x > HI0) << (j * 4 + c);
            if (x > LO0 && x <= HI0) {
                wib |= 1u << (j * 4 + c);
                if (myn < SLOTS) sval[sbase + myn] = x;
                ++myn;
            }
        }
    }
    const int mynv = myn > SLOTS ? SLOTS : myn;

    // ---- One combined block reduce: argmax + #(>HI0) + window count + overflow ----
    {
        float am = bmax; int ai = bmi;
        int rh = __popc(hib), rw = myn, ro = (myn > SLOTS) ? 1 : 0;
        #pragma unroll
        for (int off = 32; off > 0; off >>= 1) {
            float ov = __shfl_down(am, off); int ai2 = __shfl_down(ai, off);
            int o1 = __shfl_down(rh, off), o2 = __shfl_down(rw, off), o3 = __shfl_down(ro, off);
            if (ov > am || (ov == am && ai2 < ai)) { am = ov; ai = ai2; }
            rh += o1; rw += o2; ro |= o3;
        }
        if (lane == 0) { redf[wid] = am; redi[wid] = ai; whi[wid] = rh; wwin[wid] = rw; wovf[wid] = ro; }
    }
    __syncthreads();   // also orders hist zeroing before histogram atomics
    float mv = redf[0]; int mi = redi[0];
    int g_hi0 = 0, win = 0, anyovf = 0;
    #pragma unroll
    for (int w = 0; w < NWV; ++w) {
        if (redf[w] > mv || (redf[w] == mv && redi[w] < mi)) { mv = redf[w]; mi = redi[w]; }
        g_hi0 += whi[w]; win += wwin[w]; anyovf |= wovf[w];
    }
    const int need = (GTMAX + 1) - g_hi0;   // rank-from-top within the window
    const bool valid = (!anyovf) && (g_hi0 <= GTMAX) && (need <= win);

    float th = 0.f;
    bool done = false;   // block-uniform throughout

    if (valid) {
        // ---- Counting refinement: histogram stash, suffix-scan, exact tiny rank ----
        for (int k = 0; k < mynv; ++k)
            atomicAdd(&hist[bucket_of(sval[sbase + k])], 1);
        __syncthreads();
        const int h0 = hist[2 * t], h1 = hist[2 * t + 1];
        const int lsum = h0 + h1;
        int incl = lsum;                        // wave suffix-inclusive scan
        #pragma unroll
        for (int off = 1; off < 64; off <<= 1) {
            int v = __shfl_down(incl, off);
            incl += (lane + off < 64) ? v : 0;
        }
        if (lane == 0) wtot[wid] = incl;        // wave total
        __syncthreads();
        int suf = incl - lsum;                  // count in strictly-higher buckets (my wave)
        #pragma unroll
        for (int w = 0; w < NWV; ++w) suf += (w > wid) ? wtot[w] : 0;
        int running = suf;                      // above bucket 2t+1
        if (running < need && need <= running + h1) { s_bstar = 2 * t + 1; s_above = running; }
        running += h1;                          // above bucket 2t
        if (running < need && need <= running + h0) { s_bstar = 2 * t;     s_above = running; }
        __syncthreads();
        const int bstar = s_bstar, above = s_above;
        const int cnum = hist[bstar];           // block-uniform
        if (cnum <= 64) {
            for (int k = 0; k < mynv; ++k) {
                float x = sval[sbase + k];
                if (bucket_of(x) == bstar) { int pos = atomicAdd(&s_nc, 1); cands[pos] = x; }
            }
            __syncthreads();
            const int m = s_nc;                 // == cnum, usually 1-2
            for (int i = t; i < m; i += NT) {
                float ci = cands[i];
                int gt = 0, eq = 0;
                for (int j2 = 0; j2 < m; ++j2) {
                    float cj = cands[j2];
                    gt += (cj > ci) ? 1 : 0; eq += (cj == ci) ? 1 : 0;
                }
                int gg = g_hi0 + above + gt;
                if (gg <= GTMAX && gg + eq >= GTMAX + 1) s_th = ci;
            }
            __syncthreads();
            th = s_th;
            done = true;
        }
    }
    const bool fb = !done;
    if (fb) {
        // ---- Exact fallback (rare, ~0.4%/launch): value bisection re-reading tgt ----
        float lo = -1.0f, hi = mv;
        int g_lo = HW, g_hi = 0;
        bool degen = false;
        while (g_lo - g_hi > 48) {
            float mid = 0.5f * (lo + hi);
            if (!(mid > lo && mid < hi)) { degen = true; break; }
            int cnt = 0;
            for (int j = 0; j < V4; ++j) {
                float4 v = t4[j * NT + t];
                cnt += (v.x > mid) + (v.y > mid) + (v.z > mid) + (v.w > mid);
            }
            #pragma unroll
            for (int off = 32; off > 0; off >>= 1) cnt += __shfl_down(cnt, off);
            if (lane == 0) wcnt[wid] = cnt;
            __syncthreads();
            int g = 0;
            #pragma unroll
            for (int w = 0; w < NWV; ++w) g += wcnt[w];
            __syncthreads();
            if (g >= GTMAX + 1) { lo = mid; g_lo = g; }
            else                { hi = mid; g_hi = g; }
        }
        if (degen) th = hi;
        else {
            if (t == 0) s_nc = 0;
            __syncthreads();
            for (int j = 0; j < V4; ++j) {
                float4 v = t4[j * NT + t];
                float a[4] = {v.x, v.y, v.z, v.w};
                for (int c2 = 0; c2 < 4; ++c2) {
                    float x = a[c2];
                    if (x > lo && x <= hi) { int pos = atomicAdd(&s_nc, 1); if (pos < 64) cands[pos] = x; }
                }
            }
            __syncthreads();
            int m = s_nc; m = m > 64 ? 64 : m;
            for (int i = t; i < m; i += NT) {
                float ci = cands[i];
                int gt = 0, eq = 0;
                for (int j2 = 0; j2 < m; ++j2) {
                    float cj = cands[j2];
                    gt += (cj > ci) ? 1 : 0; eq += (cj == ci) ? 1 : 0;
                }
                int gg = g_hi + gt;
                if (gg <= GTMAX && gg + eq >= GTMAX + 1) s_th = ci;
            }
            __syncthreads();
            th = s_th;
        }
    }

    // ---- Pass 2: stream pred once; mask from hi-bits + stash pops; Gaussian inline.
    // g = exp(-d2/8) only within the 31x31 box (outside g<=1.3e-14; error ~1e-11).
    const int cyi = mi >> 7, cxi = mi & 127;
    float sum = 0.f;
    if (!fb) {
        float4 pa[V4];
        #pragma unroll
        for (int j = 0; j < V4; ++j) pa[j] = p4[j * NT + t];
        int k = 0;
        #pragma unroll
        for (int j = 0; j < V4; ++j) {
            const int base = (j * NT + t) * 4;
            float ap[4] = {pa[j].x, pa[j].y, pa[j].z, pa[j].w};
            #pragma unroll
            for (int c = 0; c < 4; ++c) {
                bool m = (hib >> (j * 4 + c)) & 1u;
                if ((wib >> (j * 4 + c)) & 1u) { float x = sval[sbase + k]; ++k; m = (x > th); }
                if (m) {
                    const int idx = base + c;
                    const int dy = (idx >> 7) - cyi, dx = (idx & 127) - cxi;
                    float p = ap[c];
                    if (dy >= -15 && dy <= 15 && dx >= -15 && dx <= 15) {
                        float g = __expf((float)(dy * dy + dx * dx) * -0.125f);
                        float d = p - g;
                        sum += d * d;
                    } else {
                        sum += p * p;
                    }
                }
            }
        }
    } else {
        for (int j = 0; j < V4; ++j) {
            const int vi = j * NT + t;
            float4 tv = t4[vi];
            float4 p  = p4[vi];
            const int base = vi * 4;
            float at[4] = {tv.x, tv.y, tv.z, tv.w};
            float ap[4] = {p.x, p.y, p.z, p.w};
            for (int c = 0; c < 4; ++c) {
                if (at[c] > th) {
                    const int idx = base + c;
                    const int dy = (idx >> 7) - cyi, dx = (idx & 127) - cxi;
                    float pv = ap[c];
                    if (dy >= -15 && dy <= 15 && dx >= -15 && dx <= 15) {
                        float g = __expf((float)(dy * dy + dx * dx) * -0.125f);
                        float d = pv - g;
                        sum += d * d;
                    } else {
                        sum += pv * pv;
                    }
                }
            }
        }
    }

    // ---- Block reduce, one plain store ----
    #pragma unroll
    for (int off = 32; off > 0; off >>= 1) sum += __shfl_down(sum, off);
    __syncthreads();                 // redf reuse guard
    if (lane == 0) redf[wid] = sum;
    __syncthreads();
    if (t == 0) {
        float s = 0.f;
        #pragma unroll
        for (int w = 0; w < NWV; ++w) s += redf[w];
        partial[bid] = s;
    }
}

__global__ __launch_bounds__(256) void wreg_final(
    const float* __restrict__ partial, float* __restrict__ out)
{
    __shared__ float red[4];
    const int t = threadIdx.x;
    float s = 0.f;
    for (int i = t; i < NSLICE; i += 256) s += partial[i];
    #pragma unroll
    for (int off = 32; off > 0; off >>= 1) s += __shfl_down(s, off);
    if ((t & 63) == 0) red[t >> 6] = s;
    __syncthreads();
    if (t == 0)
        out[0] = ((red[0] + red[1]) + (red[2] + red[3]))
                 * (1.0f / ((float)(HW / 4) * (float)NSLICE));  // / pxl_num / (B*K)
}

extern "C" void kernel_launch(void* const* d_in, const int* in_sizes, int n_in,
                              void* d_out, int out_size, void* d_ws, size_t ws_size,
                              hipStream_t stream)
{
    const float* pred = (const float*)d_in[0];   // "output" in reference
    const float* tgt  = (const float*)d_in[1];   // "target"
    float* partial = (float*)d_ws;               // 1088 floats scratch
    float* out     = (float*)d_out;

    wreg_fused<<<NSLICE, NT, 0, stream>>>(pred, tgt, partial);
    wreg_final<<<1, 256, 0, stream>>>(partial, out);
}